// Round 2
// baseline (236.082 us; speedup 1.0000x reference)
//
#include <hip/hip_runtime.h>

#define BATCH 4096
#define N 64

// Broadcast a float from lane `ps` (wave-uniform SGPR lane index) to all lanes.
// v_readlane_b32 -> SGPR; folds as scalar operand into the consuming v_fma.
__device__ __forceinline__ float lanebcast(float v, int ps) {
    return __uint_as_float(__builtin_amdgcn_readlane(__float_as_uint(v), ps));
}

__global__ __launch_bounds__(256, 4) void restricted_det_kernel(
    const float* __restrict__ U,
    const int* __restrict__ idx_up,
    const int* __restrict__ idx_dn,
    float* __restrict__ out)
{
    const int lane = threadIdx.x & 63;
    const int wid = (int)((blockIdx.x * blockDim.x + threadIdx.x) >> 6);  // sample id
    if (wid >= BATCH) return;

    float sgn = 1.0f;
    float logabs = 0.0f;

    #pragma unroll 1
    for (int spin = 0; spin < 2; ++spin) {
        const int* __restrict__ idx = spin ? idx_dn : idx_up;
        const int site = idx[wid * N + lane];

        // lane i holds row i of the gathered matrix, in registers
        float a[N];
        const float4* __restrict__ row = reinterpret_cast<const float4*>(U + site * N);
        #pragma unroll
        for (int q = 0; q < N / 4; ++q) {
            float4 v = row[q];
            a[4 * q + 0] = v.x;
            a[4 * q + 1] = v.y;
            a[4 * q + 2] = v.z;
            a[4 * q + 3] = v.w;
        }

        unsigned long long chosen = 0ull;  // wave-uniform: lanes already used as pivot
        int inv = 0;                       // permutation inversion count (parity)

        #pragma unroll
        for (int k = 0; k < N; ++k) {
            // ---- pivot search over column k among not-yet-chosen rows ----
            const bool cand = ((chosen >> lane) & 1ull) == 0ull;
            float key = cand ? __builtin_fabsf(a[k]) : -1.0f;
            int p = lane;
            #pragma unroll
            for (int off = 32; off >= 1; off >>= 1) {
                float key2 = __shfl_xor(key, off, 64);
                int p2 = __shfl_xor(p, off, 64);
                // total order (key desc, lane asc) -> all lanes converge to same p
                if (key2 > key || (key2 == key && p2 < p)) { key = key2; p = p2; }
            }
            const int ps = __builtin_amdgcn_readfirstlane(p);

            // parity: new inversions = #already-chosen rows with index > p
            inv += __popcll(chosen >> ps);
            chosen |= (1ull << ps);

            // ---- accumulate pivot into sign/log ----
            const float pv = lanebcast(a[k], ps);
            sgn = (pv < 0.0f) ? -sgn : sgn;
            logabs += __logf(__builtin_fabsf(pv));

            // ---- rank-1 trailing update (rows not yet chosen, excl. pivot) ----
            const bool act = ((chosen >> lane) & 1ull) == 0ull;
            const float m = act ? __fdividef(a[k], pv) : 0.0f;
            #pragma unroll
            for (int j = k + 1; j < N; ++j) {
                const float uv = lanebcast(a[j], ps);  // pivot row elem (SGPR)
                a[j] = __builtin_fmaf(-m, uv, a[j]);
            }
        }
        if (inv & 1) sgn = -sgn;
    }

    if (lane == 0) {
        out[wid] = sgn;            // output 0: sign_up * sign_dn
        out[BATCH + wid] = logabs; // output 1: logabs_up + logabs_dn
    }
}

extern "C" void kernel_launch(void* const* d_in, const int* in_sizes, int n_in,
                              void* d_out, int out_size, void* d_ws, size_t ws_size,
                              hipStream_t stream) {
    const float* U      = (const float*)d_in[0];
    const int*   idx_up = (const int*)d_in[1];
    const int*   idx_dn = (const int*)d_in[2];
    float* out = (float*)d_out;

    dim3 block(256);                      // 4 waves/block, 1 sample per wave
    dim3 grid((BATCH * 64) / 256);        // 4096 waves total
    hipLaunchKernelGGL(restricted_det_kernel, grid, block, 0, stream,
                       U, idx_up, idx_dn, out);
}

// Round 3
// 171.435 us; speedup vs baseline: 1.3771x; 1.3771x over previous
//
#include <hip/hip_runtime.h>

#define BATCH 4096
#define N 64

// One DPP max-reduce step: x = max(x, dpp_move(x)). No DS ops, no waits.
template<int CTRL>
__device__ __forceinline__ float dpp_max_step(float x) {
    int moved = __builtin_amdgcn_update_dpp(0, __float_as_int(x), CTRL, 0xf, 0xf, true);
    return fmaxf(x, __int_as_float(moved));
}

// Broadcast a float from wave-uniform lane ps: v_readlane -> SGPR, folds as
// scalar operand into the consuming v_fma.
__device__ __forceinline__ float lanebcast(float v, int ps) {
    return __uint_as_float(__builtin_amdgcn_readlane(__float_as_uint(v), ps));
}

// no min-waves clamp: ~110 VGPR still yields 4 waves/SIMD (pool = 2048/SIMD),
// but frees the compiler from the 128-reg cap that forced a[] into AGPRs.
__global__ __launch_bounds__(256) void restricted_det_kernel(
    const float* __restrict__ U,
    const int* __restrict__ idx_up,
    const int* __restrict__ idx_dn,
    float* __restrict__ out)
{
    const int lane = threadIdx.x & 63;
    const int wid  = (int)((blockIdx.x * blockDim.x + threadIdx.x) >> 6);  // sample

    // grid exactly covers BATCH waves -> no bounds check, all 64 lanes active.
    const int site0 = idx_up[wid * N + lane];
    const int site1 = idx_dn[wid * N + lane];

    float l2sum = 0.0f;           // sum of log2|pivot| over both dets
    unsigned int sbits = 0u;      // xor of pivot sign bits (wave-uniform, SALU)
    int inv = 0;                  // permutation inversion count (wave-uniform)

    #pragma unroll 1
    for (int spin = 0; spin < 2; ++spin) {
        const int site = (spin == 0) ? site0 : site1;

        // lane i holds row i of the gathered matrix, in registers
        float a[N];
        const float4* __restrict__ row = reinterpret_cast<const float4*>(U + (long)site * N);
        #pragma unroll
        for (int q = 0; q < N / 4; ++q) {
            float4 v = row[q];
            a[4*q+0] = v.x; a[4*q+1] = v.y; a[4*q+2] = v.z; a[4*q+3] = v.w;
        }

        unsigned long long chosen = 0ull;  // uniform: rows already used as pivot
        bool alive = true;                 // per-lane: row not yet pivoted

        #pragma unroll
        for (int k = 0; k < N; ++k) {
            // ---- pivot = argmax |a[k]| over live lanes (DPP tree, 6 steps) ----
            const float key = alive ? __builtin_fabsf(a[k]) : -1.0f;
            float r = key;
            r = dpp_max_step<0x111>(r);   // row_shr:1
            r = dpp_max_step<0x112>(r);   // row_shr:2
            r = dpp_max_step<0x114>(r);   // row_shr:4
            r = dpp_max_step<0x118>(r);   // row_shr:8   -> lane15 of each row-of-16
            r = dpp_max_step<0x142>(r);   // row_bcast15 -> lane31/63 merge prev row
            r = dpp_max_step<0x143>(r);   // row_bcast31 -> lane63 = wave max
            const float mx = __uint_as_float(
                __builtin_amdgcn_readlane(__float_as_uint(r), 63));  // SGPR
            const unsigned long long bal = __ballot(key == mx);      // live lanes only
            const int ps = (int)__builtin_ctzll(bal);                // uniform pivot lane

            // ---- parity via inversion counting (SALU) ----
            inv += __popcll(chosen >> ps);
            chosen |= (1ull << ps);
            alive = alive && (lane != ps);

            // ---- pivot value: sign (SALU xor), log-magnitude (|pv| == mx) ----
            const float pv = lanebcast(a[k], ps);
            sbits ^= __float_as_uint(pv);
            l2sum += __log2f(mx);

            // ---- rank-1 trailing update; dead/pivot lanes free-run on garbage
            //      (safe: each pivot-row elem is readlane'd before lane ps
            //       overwrites it, and dead rows are never selected again) ----
            const float rm = __builtin_amdgcn_rcpf(pv);
            const float m  = a[k] * rm;
            #pragma unroll
            for (int j = k + 1; j < N; ++j) {
                const float uv = lanebcast(a[j], ps);   // SGPR scalar operand
                a[j] = __builtin_fmaf(-m, uv, a[j]);
            }
        }
    }

    if (lane == 0) {
        const float sgn =
            (((sbits >> 31) ^ ((unsigned)inv & 1u)) != 0u) ? -1.0f : 1.0f;
        out[wid] = sgn;                                        // sign_up * sign_dn
        out[BATCH + wid] = l2sum * 0.69314718055994530942f;    // ln from log2
    }
}

extern "C" void kernel_launch(void* const* d_in, const int* in_sizes, int n_in,
                              void* d_out, int out_size, void* d_ws, size_t ws_size,
                              hipStream_t stream) {
    const float* U      = (const float*)d_in[0];
    const int*   idx_up = (const int*)d_in[1];
    const int*   idx_dn = (const int*)d_in[2];
    float* out = (float*)d_out;

    dim3 block(256);                 // 4 waves/block, 1 sample per wave
    dim3 grid((BATCH * 64) / 256);   // 4096 waves, exact cover
    hipLaunchKernelGGL(restricted_det_kernel, grid, block, 0, stream,
                       U, idx_up, idx_dn, out);
}

// Round 4
// 170.648 us; speedup vs baseline: 1.3834x; 1.0046x over previous
//
#include <hip/hip_runtime.h>

#define BATCH 4096
#define N 64

// One DPP max-reduce step: x = max(x, dpp_move(x)). No DS ops, no waits.
template<int CTRL>
__device__ __forceinline__ float dpp_max_step(float x) {
    int moved = __builtin_amdgcn_update_dpp(0, __float_as_int(x), CTRL, 0xf, 0xf, true);
    return fmaxf(x, __int_as_float(moved));
}

// Broadcast a float from wave-uniform lane ps: v_readlane -> SGPR, folds as
// scalar operand into the consuming v_fma.
__device__ __forceinline__ float lanebcast(float v, int ps) {
    return __uint_as_float(__builtin_amdgcn_readlane(__float_as_uint(v), ps));
}

// Block = exactly one wave, min-waves/EU = 1: gives the allocator the full
// 512-reg unified budget so a[64] lands in ARCH VGPRs (no accvgpr round-trips).
// Round-3 evidence: default bounds -> VGPR_Count=40 + AGPR traffic ~2.7x instrs.
__global__ __launch_bounds__(64, 1) void restricted_det_kernel(
    const float* __restrict__ U,
    const int* __restrict__ idx_up,
    const int* __restrict__ idx_dn,
    float* __restrict__ out)
{
    const int lane = threadIdx.x;      // 0..63, one wave per block
    const int wid  = blockIdx.x;       // sample id, exact cover of BATCH

    const int site0 = idx_up[wid * N + lane];
    const int site1 = idx_dn[wid * N + lane];

    float l2sum = 0.0f;           // sum of log2|pivot| over both dets
    unsigned int sbits = 0u;      // xor of pivot sign bits (wave-uniform)
    int inv = 0;                  // permutation inversion count (wave-uniform)

    #pragma unroll 1
    for (int spin = 0; spin < 2; ++spin) {
        const int site = (spin == 0) ? site0 : site1;

        // lane i holds row i of the gathered matrix, in registers
        float a[N];
        const float4* __restrict__ row = reinterpret_cast<const float4*>(U + (long)site * N);
        #pragma unroll
        for (int q = 0; q < N / 4; ++q) {
            float4 v = row[q];
            a[4*q+0] = v.x; a[4*q+1] = v.y; a[4*q+2] = v.z; a[4*q+3] = v.w;
        }

        unsigned long long chosen = 0ull;  // uniform: rows already used as pivot
        bool alive = true;                 // per-lane: row not yet pivoted

        #pragma unroll
        for (int k = 0; k < N; ++k) {
            // ---- pivot = argmax |a[k]| over live lanes (DPP tree, 6 steps) ----
            const float key = alive ? __builtin_fabsf(a[k]) : -1.0f;
            float r = key;
            r = dpp_max_step<0x111>(r);   // row_shr:1
            r = dpp_max_step<0x112>(r);   // row_shr:2
            r = dpp_max_step<0x114>(r);   // row_shr:4
            r = dpp_max_step<0x118>(r);   // row_shr:8   -> lane15 of each row-of-16
            r = dpp_max_step<0x142>(r);   // row_bcast15 -> lane31/63 merge prev row
            r = dpp_max_step<0x143>(r);   // row_bcast31 -> lane63 = wave max
            const float mx = __uint_as_float(
                __builtin_amdgcn_readlane(__float_as_uint(r), 63));  // SGPR
            const unsigned long long bal = __ballot(key == mx);      // live lanes only
            const int ps = (int)__builtin_ctzll(bal);                // uniform pivot lane

            // ---- parity via inversion counting (SALU) ----
            inv += __popcll(chosen >> ps);
            chosen |= (1ull << ps);
            alive = alive && (lane != ps);

            // ---- pivot value: sign (SALU xor), log-magnitude (|pv| == mx) ----
            const float pv = lanebcast(a[k], ps);
            sbits ^= __float_as_uint(pv);
            l2sum += __log2f(mx);

            // ---- rank-1 trailing update; dead/pivot lanes free-run on garbage
            //      (safe: each pivot-row elem is readlane'd before lane ps
            //       overwrites it, and dead rows are never selected again) ----
            const float rm = __builtin_amdgcn_rcpf(pv);
            const float m  = a[k] * rm;
            #pragma unroll
            for (int j = k + 1; j < N; ++j) {
                const float uv = lanebcast(a[j], ps);   // SGPR scalar operand
                a[j] = __builtin_fmaf(-m, uv, a[j]);
            }
        }
    }

    if (lane == 0) {
        const float sgn =
            (((sbits >> 31) ^ ((unsigned)inv & 1u)) != 0u) ? -1.0f : 1.0f;
        out[wid] = sgn;                                        // sign_up * sign_dn
        out[BATCH + wid] = l2sum * 0.69314718055994530942f;    // ln from log2
    }
}

extern "C" void kernel_launch(void* const* d_in, const int* in_sizes, int n_in,
                              void* d_out, int out_size, void* d_ws, size_t ws_size,
                              hipStream_t stream) {
    const float* U      = (const float*)d_in[0];
    const int*   idx_up = (const int*)d_in[1];
    const int*   idx_dn = (const int*)d_in[2];
    float* out = (float*)d_out;

    dim3 block(64);                  // one wave per block, 1 sample per wave
    dim3 grid(BATCH);                // 4096 waves, exact cover
    hipLaunchKernelGGL(restricted_det_kernel, grid, block, 0, stream,
                       U, idx_up, idx_dn, out);
}